// Round 4
// baseline (374.434 us; speedup 1.0000x reference)
//
#include <hip/hip_runtime.h>
#include <hip/hip_bf16.h>
#include <stdint.h>
#include <stddef.h>

#define S_LEN 2048
#define HID_DIM 2048
#define NH 16
#define D_QK 192
#define D_NOPE 128
#define D_ROPE 64
#define D_V 128
#define KV_R 512
#define CKV_N (KV_R + D_ROPE)            /* 576 */
#define KVB_N (NH * (D_NOPE + D_V))      /* 4096 */
#define QN (NH * D_QK)                   /* 3072 */
#define CAT_N (QN + CKV_N)               /* 3648: q_proj+kv_a fused N */
#define QKVA_ROWS 3840                   /* CAT_N padded to 15*256 for 256-tile GEMM */
#define QCKV_LD QKVA_ROWS                /* qckv row stride */
#define SCALING 0.07216878364870322f     /* 192^-0.5 */

typedef __attribute__((ext_vector_type(8))) short short8;
typedef __attribute__((ext_vector_type(4))) short short4v;
typedef __attribute__((ext_vector_type(4))) float f32x4;

__device__ __forceinline__ short f2bf_bits(float f) {
  unsigned u = __float_as_uint(f);
  unsigned r = (u + 0x7fffu + ((u >> 16) & 1u)) >> 16;  // RNE
  return (short)(r & 0xffffu);
}
__device__ __forceinline__ float bf2f(short b) {
  return __uint_as_float(((unsigned)(unsigned short)b) << 16);
}

__device__ __forceinline__ f32x4 mfma_bf16(short8 a, short8 b, f32x4 c) {
  return __builtin_amdgcn_mfma_f32_16x16x32_bf16(a, b, c, 0, 0, 0);
}

#define BARRIER_FENCED() do { \
    asm volatile("" ::: "memory"); \
    __builtin_amdgcn_s_barrier(); \
    asm volatile("" ::: "memory"); \
  } while (0)

// ---------------------------------------------------------------------------
// Fused f32 -> bf16 conversion of 5 tensors in one launch.
// ---------------------------------------------------------------------------
__global__ __launch_bounds__(256)
void cvt5_k(const float* __restrict__ s0, short* __restrict__ d0, int c0,
            const float* __restrict__ s1, short* __restrict__ d1, int c1,
            const float* __restrict__ s2, short* __restrict__ d2, int c2,
            const float* __restrict__ s3, short* __restrict__ d3, int c3,
            const float* __restrict__ s4, short* __restrict__ d4, int c4) {
  const int i = blockIdx.x * 256 + threadIdx.x;
  const float* s; short* d; int base;
  if      (i < c0) { s = s0; d = d0; base = 0;  }
  else if (i < c1) { s = s1; d = d1; base = c0; }
  else if (i < c2) { s = s2; d = d2; base = c1; }
  else if (i < c3) { s = s3; d = d3; base = c2; }
  else if (i < c4) { s = s4; d = d4; base = c3; }
  else return;
  const int j = i - base;
  const float4 v = ((const float4*)s)[j];
  short4v o;
  o.x = f2bf_bits(v.x); o.y = f2bf_bits(v.y);
  o.z = f2bf_bits(v.z); o.w = f2bf_bits(v.w);
  ((short4v*)d)[j] = o;
}

// ---------------------------------------------------------------------------
// 256x256x64 8-phase GEMM: C[M,N] = A[M,K] @ B[N,K]^T  (bf16 in, f32 acc).
// Port of the verified learn_hip m201 structure (T2 swizzle + T3/T4 counted
// vmcnt + T5 setprio). 8 waves (512 thr), per-wave C = 128x64 scattered as
// 2mh x 2nh quadrant pieces of 64x32. LDS 128 KiB: [buf][A/B][half][128*64].
//
// Phase schedule per iteration (tiles T=2i in buf0, T+1 in buf1):
//   ph q(mh,nh) computes quadrant of tile; stage list (hazard-ledger-derived):
//   ph0:A1(T+1) ph1:B1(T+1) ph2:A0(T+2) ph3:B0(T+2)+vmcnt(4)
//   ph4:A1(T+2) ph5:B1(T+2) ph6:A0(T+3) ph7:B0(T+3)+vmcnt(4)
//   Each stage lands after its target half's last reader barrier; vmcnt(4)
//   retains exactly the 2 newest half-tiles (not yet needed). Final iter
//   degrades to vmcnt(0).
// Swizzle: 16B-chunk index XOR (row&7); LDS dest linear, global SOURCE
// pre-inverse-swizzled (global_load_lds writes base+lane*16), reads swizzled.
// Requires M%256==0, N%256==0, K%128==0 (all call sites comply; gemm1's N
// padded to 3840 with zeroed weight rows).
// ---------------------------------------------------------------------------
template <bool OUTF32>
__global__ __launch_bounds__(512, 2)
void gemm8_k(const short* __restrict__ A, const short* __restrict__ B,
             void* __restrict__ Cv, int M, int N, int K) {
  __shared__ short lds[2][2][2][128 * 64];  // [buf][A=0/B=1][half][row*64+k]
  const int tid  = threadIdx.x;
  const int wid  = tid >> 6;
  const int lane = tid & 63;
  const int wa = wid >> 2;        // 64-row group within 128-row half
  const int wb = wid & 3;         // 32-col group within 128-col half
  const int fr = lane & 15;
  const int g  = lane >> 4;
  const int bm = blockIdx.y * 256;
  const int bn = blockIdx.x * 256;
  const int nk = K >> 6;

  auto stage_half = [&](int buf, int ab, int half, int kt) {
    const short* P = ab ? B : A;
    const int rowbase = (ab ? bn : bm) + half * 128;
    const int k0 = kt << 6;
#pragma unroll
    for (int p = 0; p < 2; ++p) {
      const int c = p * 512 + tid;          // chunk 0..1023 (16B each)
      const int r = c >> 3;                 // row 0..127
      const int sc = ((c & 7) ^ (r & 7)) << 3;  // inverse-swizzled col (shorts)
      __builtin_amdgcn_global_load_lds(
          (const __attribute__((address_space(1))) void*)(P + (size_t)(rowbase + r) * K + k0 + sc),
          (__attribute__((address_space(3))) void*)(&lds[buf][ab][half][(p * 512 + (wid << 6)) * 8]),
          16, 0, 0);
    }
  };

  f32x4 acc[2][2][4][2];
#pragma unroll
  for (int mh = 0; mh < 2; ++mh)
#pragma unroll
    for (int nh = 0; nh < 2; ++nh)
#pragma unroll
      for (int mi = 0; mi < 4; ++mi)
#pragma unroll
        for (int nj = 0; nj < 2; ++nj)
          for (int r = 0; r < 4; ++r) acc[mh][nh][mi][nj][r] = 0.f;

  // prologue: tile0 fully, tile1 halves A0,B0 -> 12 loads; keep newest 4 in flight
  stage_half(0, 0, 0, 0); stage_half(0, 0, 1, 0);
  stage_half(0, 1, 0, 0); stage_half(0, 1, 1, 0);
  stage_half(1, 0, 0, 1); stage_half(1, 1, 0, 1);
  asm volatile("s_waitcnt vmcnt(4)" ::: "memory");
  BARRIER_FENCED();

  for (int it = 0; it < (nk >> 1); ++it) {
    const int T = it << 1;
#pragma unroll
    for (int tt = 0; tt < 2; ++tt) {
#pragma unroll
      for (int q = 0; q < 4; ++q) {
        const int ph = tt * 4 + q;
        const int mh = q >> 1, nh = q & 1;

        // ---- ds-read this phase's fragments (swizzled, conflict-free) ----
        short8 af[4][2], bfm[2][2];
#pragma unroll
        for (int mi = 0; mi < 4; ++mi) {
          const int lr = wa * 64 + mi * 16 + fr;
#pragma unroll
          for (int kh = 0; kh < 2; ++kh) {
            const int byte = lr * 128 + kh * 64 + g * 16;
            const int phys = byte ^ ((lr & 7) << 4);
            af[mi][kh] = *(const short8*)((const char*)&lds[tt][0][mh][0] + phys);
          }
        }
#pragma unroll
        for (int nj = 0; nj < 2; ++nj) {
          const int lc = wb * 32 + nj * 16 + fr;
#pragma unroll
          for (int kh = 0; kh < 2; ++kh) {
            const int byte = lc * 128 + kh * 64 + g * 16;
            const int phys = byte ^ ((lc & 7) << 4);
            bfm[nj][kh] = *(const short8*)((const char*)&lds[tt][1][nh][0] + phys);
          }
        }

        // ---- stage one half-tile per ledger ----
        if (ph == 0) stage_half(1, 0, 1, T + 1);
        if (ph == 1) stage_half(1, 1, 1, T + 1);
        if (ph == 2 && T + 2 < nk) stage_half(0, 0, 0, T + 2);
        if (ph == 3 && T + 2 < nk) stage_half(0, 1, 0, T + 2);
        if (ph == 4 && T + 2 < nk) stage_half(0, 0, 1, T + 2);
        if (ph == 5 && T + 2 < nk) stage_half(0, 1, 1, T + 2);
        if (ph == 6 && T + 3 < nk) stage_half(1, 0, 0, T + 3);
        if (ph == 7 && T + 3 < nk) stage_half(1, 1, 0, T + 3);

        BARRIER_FENCED();

        __builtin_amdgcn_s_setprio(1);
#pragma unroll
        for (int mi = 0; mi < 4; ++mi)
#pragma unroll
          for (int nj = 0; nj < 2; ++nj)
#pragma unroll
            for (int kh = 0; kh < 2; ++kh)
              acc[mh][nh][mi][nj] = mfma_bf16(af[mi][kh], bfm[nj][kh], acc[mh][nh][mi][nj]);
        __builtin_amdgcn_s_setprio(0);

        if (ph == 3) {
          if (T + 2 < nk) asm volatile("s_waitcnt vmcnt(4)" ::: "memory");
          else            asm volatile("s_waitcnt vmcnt(0)" ::: "memory");
        }
        if (ph == 7) {
          if (T + 3 < nk) asm volatile("s_waitcnt vmcnt(4)" ::: "memory");
          else            asm volatile("s_waitcnt vmcnt(0)" ::: "memory");
        }
        BARRIER_FENCED();
      }
    }
  }

  // ---- epilogue: C-write (col = lane&15, row = (lane>>4)*4 + r) ----
  const int cr = (lane >> 4) * 4, ccol = lane & 15;
#pragma unroll
  for (int mh = 0; mh < 2; ++mh)
#pragma unroll
    for (int nh = 0; nh < 2; ++nh)
#pragma unroll
      for (int mi = 0; mi < 4; ++mi)
#pragma unroll
        for (int nj = 0; nj < 2; ++nj) {
          const int row0 = bm + mh * 128 + wa * 64 + mi * 16 + cr;
          const int col  = bn + nh * 128 + wb * 32 + nj * 16 + ccol;
#pragma unroll
          for (int r = 0; r < 4; ++r) {
            if (OUTF32)
              ((float*)Cv)[(size_t)(row0 + r) * N + col] = acc[mh][nh][mi][nj][r];
            else
              ((short*)Cv)[(size_t)(row0 + r) * N + col] = f2bf_bits(acc[mh][nh][mi][nj][r]);
          }
        }
}

// ---------------------------------------------------------------------------
// RMSNorm over qckv[:, 3072:3584] -> ckvn (bf16).
// ---------------------------------------------------------------------------
__global__ __launch_bounds__(256)
void rmsnorm_k(const short* __restrict__ qckv, const float* __restrict__ w,
               short* __restrict__ out) {
  const int s = blockIdx.x, t = threadIdx.x;
  const short* x = qckv + (size_t)s * QCKV_LD + QN;
  float v0 = bf2f(x[2 * t]), v1 = bf2f(x[2 * t + 1]);
  float ss = v0 * v0 + v1 * v1;
#pragma unroll
  for (int off = 1; off < 64; off <<= 1) ss += __shfl_xor(ss, off, 64);
  __shared__ float red[4];
  if ((t & 63) == 0) red[t >> 6] = ss;
  __syncthreads();
  const float tot = red[0] + red[1] + red[2] + red[3];
  const float sc = rsqrtf(tot * (1.0f / 512.0f) + 1e-6f);
  out[(size_t)s * KV_R + 2 * t]     = f2bf_bits(v0 * sc * w[2 * t]);
  out[(size_t)s * KV_R + 2 * t + 1] = f2bf_bits(v1 * sc * w[2 * t + 1]);
}

// ---------------------------------------------------------------------------
// Prep: RoPE (deinterleaved) + assemble Qs[h][s][192], Ks[h][s][192].
// ---------------------------------------------------------------------------
__global__ __launch_bounds__(256)
void prep_k(const short* __restrict__ qckv, const short* __restrict__ kvb,
            const float* __restrict__ cosb, const float* __restrict__ sinb,
            short* __restrict__ Qs, short* __restrict__ Ks) {
  const int s = blockIdx.x, t = threadIdx.x;
  const short* qrow = qckv + (size_t)s * QCKV_LD;
  __shared__ float cs[32], sn[32];
  __shared__ short krs[64];
  if (t < 32) {
    const float c  = cosb[(size_t)s * 64 + t];
    const float si = sinb[(size_t)s * 64 + t];
    cs[t] = c; sn[t] = si;
    const float e0 = bf2f(qrow[QN + KV_R + 2 * t]);
    const float e1 = bf2f(qrow[QN + KV_R + 2 * t + 1]);
    krs[t]      = f2bf_bits(e0 * c - e1 * si);
    krs[t + 32] = f2bf_bits(e1 * c + e0 * si);
  }
  __syncthreads();
  const int h = t >> 4, i = t & 15;
  *(short8*)(Qs + ((size_t)h * S_LEN + s) * D_QK + i * 8) =
      *(const short8*)(qrow + h * D_QK + i * 8);
  *(short8*)(Ks + ((size_t)h * S_LEN + s) * D_QK + i * 8) =
      *(const short8*)(kvb + (size_t)s * KVB_N + h * 256 + i * 8);
#pragma unroll
  for (int p = 0; p < 2; ++p) {
    const int ii = i * 2 + p;  // 0..31
    const float e0 = bf2f(qrow[h * D_QK + 128 + 2 * ii]);
    const float e1 = bf2f(qrow[h * D_QK + 128 + 2 * ii + 1]);
    Qs[((size_t)h * S_LEN + s) * D_QK + 128 + ii] = f2bf_bits(e0 * cs[ii] - e1 * sn[ii]);
    Qs[((size_t)h * S_LEN + s) * D_QK + 160 + ii] = f2bf_bits(e1 * cs[ii] + e0 * sn[ii]);
  }
#pragma unroll
  for (int p = 0; p < 4; ++p) {
    const int idx = t * 4 + p;          // 0..1023
    const int hh = idx >> 6, ii = idx & 63;
    Ks[((size_t)hh * S_LEN + s) * D_QK + 128 + ii] = krs[ii];
  }
}

// ---------------------------------------------------------------------------
// V transpose via LDS tile: Vt[h][d][s] = kvb[s][h*256+128+d].
// ---------------------------------------------------------------------------
__global__ __launch_bounds__(256)
void vtr_k(const short* __restrict__ kvb, short* __restrict__ Vt) {
  const int st = blockIdx.x, dt = blockIdx.y, h = blockIdx.z;
  __shared__ short sT[64][72];
  const int id = threadIdx.x;
#pragma unroll
  for (int p = 0; p < 2; ++p) {
    const int q = id + p * 256;
    const int row = q >> 3, c8 = q & 7;
    *(short8*)(&sT[row][c8 * 8]) =
        *(const short8*)(kvb + (size_t)(st * 64 + row) * KVB_N + h * 256 + 128 + dt * 64 + c8 * 8);
  }
  __syncthreads();
#pragma unroll
  for (int p = 0; p < 2; ++p) {
    const int q = id + p * 256;
    const int drow = q >> 3, c8 = q & 7;
    short8 o;
#pragma unroll
    for (int j = 0; j < 8; ++j) o[j] = sT[c8 * 8 + j][drow];
    *(short8*)(Vt + ((size_t)h * D_V + dt * 64 + drow) * S_LEN + st * 64 + c8 * 8) = o;
  }
}

// ---------------------------------------------------------------------------
// Flash attention (Round-0 version, measured ~86 us): 512 blocks, one 64-row
// q-tile per block, heavy-first, 2 blocks/CU, register-prefetch pipeline.
// ---------------------------------------------------------------------------
__global__ __launch_bounds__(256, 2)
void flash_k(const short* __restrict__ Qs, const short* __restrict__ Ks,
             const short* __restrict__ Vt, short* __restrict__ Oc) {
  __shared__ short sK[64 * 200];        // 25.6 KB
  __shared__ short sVt[128 * 72];       // 18.4 KB
  __shared__ short P_lds[4][16 * 72];   //  9.2 KB
  const int tid = threadIdx.x;
  const int wv = tid >> 6;
  const int lane = tid & 63;
  const int blk = blockIdx.x;                          // 0..511
  const int h = ((blk & 7) << 1) | ((blk >> 3) & 1);   // 2 heads per XCD
  const int qb = 31 - (blk >> 4);                      // heavy q-blocks first
  const int q0 = qb * 64 + wv * 16;
  const int fr = lane & 15, g = lane >> 4;

  const short* Qh = Qs + (size_t)h * S_LEN * D_QK;
  const short* Kh = Ks + (size_t)h * S_LEN * D_QK;
  const short* Vh = Vt + (size_t)h * D_V * S_LEN;

  // loop-invariant staging coordinates
  int rowK[6], c8K[6], rowV[4], c8V[4];
#pragma unroll
  for (int p = 0; p < 6; ++p) {
    const int id = tid + p * 256;
    rowK[p] = id / 24; c8K[p] = id % 24;
  }
#pragma unroll
  for (int p = 0; p < 4; ++p) {
    const int id = tid + p * 256;
    rowV[p] = id >> 3; c8V[p] = id & 7;
  }

  short8 qa[6];
#pragma unroll
  for (int c = 0; c < 6; ++c)
    qa[c] = *(const short8*)(Qh + (size_t)(q0 + fr) * D_QK + c * 32 + g * 8);

  f32x4 o[8];
  for (int f = 0; f < 8; ++f)
    for (int r = 0; r < 4; ++r) o[f][r] = 0.f;
  float m_i[4] = {-1e30f, -1e30f, -1e30f, -1e30f};
  float l_i[4] = {0.f, 0.f, 0.f, 0.f};

  // prefetch tile 0
  short8 kc[6], vc[4];
#pragma unroll
  for (int p = 0; p < 6; ++p)
    kc[p] = *(const short8*)(Kh + (size_t)rowK[p] * D_QK + c8K[p] * 8);
#pragma unroll
  for (int p = 0; p < 4; ++p)
    vc[p] = *(const short8*)(Vh + (size_t)rowV[p] * S_LEN + c8V[p] * 8);

  short* pl = &P_lds[wv][0];
  const int jn = qb + 1;
  for (int jt = 0; jt < jn; ++jt) {
    const int j0 = jt << 6;
    // ---- commit prefetched tile to LDS ----
    __syncthreads();
#pragma unroll
    for (int p = 0; p < 6; ++p)
      *(short8*)(sK + rowK[p] * 200 + c8K[p] * 8) = kc[p];
#pragma unroll
    for (int p = 0; p < 4; ++p)
      *(short8*)(sVt + rowV[p] * 72 + c8V[p] * 8) = vc[p];
    __syncthreads();
    // ---- issue next tile's global loads (consumed next iteration) ----
    if (jt + 1 < jn) {
      const int j1 = (jt + 1) << 6;
#pragma unroll
      for (int p = 0; p < 6; ++p)
        kc[p] = *(const short8*)(Kh + (size_t)(j1 + rowK[p]) * D_QK + c8K[p] * 8);
#pragma unroll
      for (int p = 0; p < 4; ++p)
        vc[p] = *(const short8*)(Vh + (size_t)rowV[p] * S_LEN + j1 + c8V[p] * 8);
    }

    // ---- QK^T from LDS; skip fully-masked 16-key sub-tiles (wave-uniform) --
    f32x4 sc[4];
#pragma unroll
    for (int t = 0; t < 4; ++t)
      for (int r = 0; r < 4; ++r) sc[t][r] = -1e30f;
#pragma unroll
    for (int t = 0; t < 4; ++t) {
      if (j0 + t * 16 <= q0 + 15) {
        f32x4 a;
        for (int r = 0; r < 4; ++r) a[r] = 0.f;
        const short* kr = sK + (t * 16 + fr) * 200 + g * 8;
#pragma unroll
        for (int c = 0; c < 6; ++c)
          a = mfma_bf16(qa[c], *(const short8*)(kr + c * 32), a);
        sc[t] = a;
      }
    }
    // ---- scale + causal mask + per-row tile max ----
    float tm[4];
#pragma unroll
    for (int r = 0; r < 4; ++r) {
      const int row = q0 + g * 4 + r;
      float mx = -1e30f;
#pragma unroll
      for (int t = 0; t < 4; ++t) {
        const float v = (j0 + t * 16 + fr <= row) ? sc[t][r] * SCALING : -1e30f;
        sc[t][r] = v;
        mx = fmaxf(mx, v);
      }
      tm[r] = mx;
    }
#pragma unroll
    for (int off = 1; off < 16; off <<= 1)
#pragma unroll
      for (int r = 0; r < 4; ++r)
        tm[r] = fmaxf(tm[r], __shfl_xor(tm[r], off, 16));
    // ---- online softmax update ----
    float ps[4];
#pragma unroll
    for (int r = 0; r < 4; ++r) {
      const float mnew = fmaxf(m_i[r], tm[r]);
      const float alpha = __expf(m_i[r] - mnew);
      m_i[r] = mnew;
      l_i[r] *= alpha;
      float s = 0.f;
#pragma unroll
      for (int t = 0; t < 4; ++t) {
        const float p = __expf(sc[t][r] - mnew);
        sc[t][r] = p;
        s += p;
      }
      ps[r] = s;
#pragma unroll
      for (int f = 0; f < 8; ++f) o[f][r] *= alpha;
    }
#pragma unroll
    for (int off = 1; off < 16; off <<= 1)
#pragma unroll
      for (int r = 0; r < 4; ++r)
        ps[r] += __shfl_xor(ps[r], off, 16);
#pragma unroll
    for (int r = 0; r < 4; ++r) l_i[r] += ps[r];

    // ---- P (C-layout) -> per-wave LDS -> A-frag ----
#pragma unroll
    for (int r = 0; r < 4; ++r)
#pragma unroll
      for (int t = 0; t < 4; ++t)
        pl[(g * 4 + r) * 72 + t * 16 + fr] = f2bf_bits(sc[t][r]);
    __builtin_amdgcn_fence(__ATOMIC_ACQ_REL, "wavefront");
    const short8 pa0 = *(const short8*)(pl + fr * 72 + g * 8);
    const short8 pa1 = *(const short8*)(pl + fr * 72 + 32 + g * 8);

    // ---- PV from LDS V^T tile ----
#pragma unroll
    for (int f = 0; f < 8; ++f) {
      const short* vr = sVt + (f * 16 + fr) * 72 + g * 8;
      const short8 vb0 = *(const short8*)(vr);
      const short8 vb1 = *(const short8*)(vr + 32);
      o[f] = mfma_bf16(pa1, vb1, mfma_bf16(pa0, vb0, o[f]));
    }
  }

#pragma unroll
  for (int r = 0; r < 4; ++r) {
    const float inv = 1.0f / l_i[r];
    const int row = q0 + g * 4 + r;
#pragma unroll
    for (int f = 0; f < 8; ++f)
      Oc[(size_t)row * (NH * D_V) + h * D_V + f * 16 + fr] = f2bf_bits(o[f][r] * inv);
  }
}

// ---------------------------------------------------------------------------
extern "C" void kernel_launch(void* const* d_in, const int* in_sizes, int n_in,
                              void* d_out, int out_size, void* d_ws, size_t ws_size,
                              hipStream_t stream) {
  const float* hidden = (const float*)d_in[0];
  const float* cosb   = (const float*)d_in[1];
  const float* sinb   = (const float*)d_in[2];
  /* d_in[3] attention_mask: causal, applied analytically */
  const float* q_w    = (const float*)d_in[4];
  const float* kva_w  = (const float*)d_in[5];
  const float* ln_w   = (const float*)d_in[6];
  const float* kvb_w  = (const float*)d_in[7];
  const float* o_w    = (const float*)d_in[8];
  float* out = (float*)d_out;

  char* ws = (char*)d_ws;
  size_t off = 0;
  auto alloc = [&](size_t elems) {
    short* p = (short*)(ws + off);
    off += ((elems * 2 + 255) & ~(size_t)255);
    return p;
  };
  short* hid_b   = alloc((size_t)S_LEN * HID_DIM);
  short* qkva_wb = alloc((size_t)QKVA_ROWS * HID_DIM); // q_w rows, kva_w rows, zero pad
  short* kvb_wb  = alloc((size_t)KVB_N * KV_R);
  short* o_wb    = alloc((size_t)HID_DIM * NH * D_V);
  short* qckv    = alloc((size_t)S_LEN * QCKV_LD);     // fused q + ckv output (padded)
  short* ckvn    = alloc((size_t)S_LEN * KV_R);
  short* kvb     = alloc((size_t)S_LEN * KVB_N);
  short* Qs      = alloc((size_t)NH * S_LEN * D_QK);
  short* Ks      = alloc((size_t)NH * S_LEN * D_QK);
  short* Vt      = alloc((size_t)NH * D_V * S_LEN);
  short* Oc      = alloc((size_t)S_LEN * NH * D_V);

  dim3 blk(256);
  // zero the padded weight rows (3648..3839) so padded GEMM columns are finite
  hipMemsetAsync(qkva_wb + (size_t)CAT_N * HID_DIM, 0,
                 (size_t)(QKVA_ROWS - CAT_N) * HID_DIM * 2, stream);

  const int n0 = (S_LEN * HID_DIM) / 4;
  const int n1 = (QN * HID_DIM) / 4;
  const int n2 = (CKV_N * HID_DIM) / 4;
  const int n3 = (KVB_N * KV_R) / 4;
  const int n4e = (HID_DIM * NH * D_V) / 4;
  const int c0 = n0, c1 = c0 + n1, c2 = c1 + n2, c3 = c2 + n3, c4 = c3 + n4e;
  cvt5_k<<<dim3((c4 + 255) / 256), blk, 0, stream>>>(
      hidden, hid_b, c0,
      q_w, qkva_wb, c1,
      kva_w, qkva_wb + (size_t)QN * HID_DIM, c2,
      kvb_w, kvb_wb, c3,
      o_w, o_wb, c4);

  gemm8_k<false><<<dim3(QKVA_ROWS / 256, S_LEN / 256), dim3(512), 0, stream>>>(
      hid_b, qkva_wb, qckv, S_LEN, QKVA_ROWS, HID_DIM);
  rmsnorm_k<<<dim3(S_LEN), blk, 0, stream>>>(qckv, ln_w, ckvn);
  gemm8_k<false><<<dim3(KVB_N / 256, S_LEN / 256), dim3(512), 0, stream>>>(
      ckvn, kvb_wb, kvb, S_LEN, KVB_N, KV_R);
  prep_k<<<dim3(S_LEN), blk, 0, stream>>>(qckv, kvb, cosb, sinb, Qs, Ks);
  vtr_k<<<dim3(S_LEN / 64, D_V / 64, NH), blk, 0, stream>>>(kvb, Vt);
  flash_k<<<dim3(NH * 128 / 4), blk, 0, stream>>>(Qs, Ks, Vt, Oc);
  gemm8_k<true><<<dim3(HID_DIM / 256, S_LEN / 256), dim3(512), 0, stream>>>(
      Oc, o_wb, out, S_LEN, HID_DIM, NH * D_V);
}

// Round 5
// 359.834 us; speedup vs baseline: 1.0406x; 1.0406x over previous
//
#include <hip/hip_runtime.h>
#include <hip/hip_bf16.h>
#include <stdint.h>
#include <stddef.h>

#define S_LEN 2048
#define HID_DIM 2048
#define NH 16
#define D_QK 192
#define D_NOPE 128
#define D_ROPE 64
#define D_V 128
#define KV_R 512
#define CKV_N (KV_R + D_ROPE)            /* 576 */
#define KVB_N (NH * (D_NOPE + D_V))      /* 4096 */
#define QN (NH * D_QK)                   /* 3072 */
#define CAT_N (QN + CKV_N)               /* 3648: q_proj+kv_a fused N */
#define QKVA_ROWS 3840                   /* CAT_N padded to 15*256 for 256-tile GEMM */
#define QCKV_LD QKVA_ROWS                /* qckv row stride */
#define SCALING 0.07216878364870322f     /* 192^-0.5 */

typedef __attribute__((ext_vector_type(8))) short short8;
typedef __attribute__((ext_vector_type(4))) short short4v;
typedef __attribute__((ext_vector_type(4))) float f32x4;

__device__ __forceinline__ short f2bf_bits(float f) {
  unsigned u = __float_as_uint(f);
  unsigned r = (u + 0x7fffu + ((u >> 16) & 1u)) >> 16;  // RNE
  return (short)(r & 0xffffu);
}
__device__ __forceinline__ float bf2f(short b) {
  return __uint_as_float(((unsigned)(unsigned short)b) << 16);
}

__device__ __forceinline__ f32x4 mfma_bf16(short8 a, short8 b, f32x4 c) {
  return __builtin_amdgcn_mfma_f32_16x16x32_bf16(a, b, c, 0, 0, 0);
}

#define BARRIER_FENCED() do { \
    asm volatile("" ::: "memory"); \
    __builtin_amdgcn_s_barrier(); \
    asm volatile("" ::: "memory"); \
  } while (0)

// ---------------------------------------------------------------------------
// Fused f32 -> bf16 conversion of 5 tensors in one launch.
// ---------------------------------------------------------------------------
__global__ __launch_bounds__(256)
void cvt5_k(const float* __restrict__ s0, short* __restrict__ d0, int c0,
            const float* __restrict__ s1, short* __restrict__ d1, int c1,
            const float* __restrict__ s2, short* __restrict__ d2, int c2,
            const float* __restrict__ s3, short* __restrict__ d3, int c3,
            const float* __restrict__ s4, short* __restrict__ d4, int c4) {
  const int i = blockIdx.x * 256 + threadIdx.x;
  const float* s; short* d; int base;
  if      (i < c0) { s = s0; d = d0; base = 0;  }
  else if (i < c1) { s = s1; d = d1; base = c0; }
  else if (i < c2) { s = s2; d = d2; base = c1; }
  else if (i < c3) { s = s3; d = d3; base = c2; }
  else if (i < c4) { s = s4; d = d4; base = c3; }
  else return;
  const int j = i - base;
  const float4 v = ((const float4*)s)[j];
  short4v o;
  o.x = f2bf_bits(v.x); o.y = f2bf_bits(v.y);
  o.z = f2bf_bits(v.z); o.w = f2bf_bits(v.w);
  ((short4v*)d)[j] = o;
}

// ---------------------------------------------------------------------------
// 256x256x64 8-phase GEMM: C[M,N] = A[M,K] @ B[N,K]^T  (bf16 in, f32 acc).
// m201-structure port. R4 post-mortem: per-phase quadrant re-reads doubled
// LDS-read traffic (96 b128/wave/iter) -> LDS-read-bound. R5 fix: Gray-code
// quadrant order (0,0)->(0,1)->(1,1)->(1,0) with fragment reuse:
//   ph+0: read A-half0 (8) + B-half0 (4, persists all 4 phases)
//   ph+1: read B-half1 (4)           (reuse A-half0)
//   ph+2: read A-half1 (8)           (reuse B-half1)
//   ph+3: no reads                   (reuse A-half1 + B-half0)
// = 24 b128/K-tile = m201's density. Stage/vmcnt ledger unchanged from R4
// (re-verified: every half's last LDS-read precedes its restage phase):
//   ph0:A1(T+1) ph1:B1(T+1) ph2:A0(T+2) ph3:B0(T+2)+vmcnt(4)
//   ph4:A1(T+2) ph5:B1(T+2) ph6:A0(T+3) ph7:B0(T+3)+vmcnt(4)
// Swizzle: 16B-chunk XOR (row&7); linear LDS dest + inverse-swizzled global
// source (global_load_lds writes base+lane*16) + swizzled ds_read.
// ---------------------------------------------------------------------------
template <bool OUTF32>
__global__ __launch_bounds__(512, 2)
void gemm8_k(const short* __restrict__ A, const short* __restrict__ B,
             void* __restrict__ Cv, int M, int N, int K) {
  __shared__ short lds[2][2][2][128 * 64];  // [buf][A=0/B=1][half][row*64+k]
  const int tid  = threadIdx.x;
  const int wid  = tid >> 6;
  const int lane = tid & 63;
  const int wa = wid >> 2;        // 64-row group within 128-row half
  const int wb = wid & 3;         // 32-col group within 128-col half
  const int fr = lane & 15;
  const int g  = lane >> 4;
  const int bm = blockIdx.y * 256;
  const int bn = blockIdx.x * 256;
  const int nk = K >> 6;

  auto stage_half = [&](int buf, int ab, int half, int kt) {
    const short* P = ab ? B : A;
    const int rowbase = (ab ? bn : bm) + half * 128;
    const int k0 = kt << 6;
#pragma unroll
    for (int p = 0; p < 2; ++p) {
      const int c = p * 512 + tid;          // chunk 0..1023 (16B each)
      const int r = c >> 3;                 // row 0..127
      const int sc = ((c & 7) ^ (r & 7)) << 3;  // inverse-swizzled col (shorts)
      __builtin_amdgcn_global_load_lds(
          (const __attribute__((address_space(1))) void*)(P + (size_t)(rowbase + r) * K + k0 + sc),
          (__attribute__((address_space(3))) void*)(&lds[buf][ab][half][(p * 512 + (wid << 6)) * 8]),
          16, 0, 0);
    }
  };

  // swizzled fragment reads (compile-time tt/mh/nh at every call site)
  auto ld_a = [&](short8 (&af)[4][2], int tt, int mh) {
#pragma unroll
    for (int mi = 0; mi < 4; ++mi) {
      const int lr = wa * 64 + mi * 16 + fr;
#pragma unroll
      for (int kh = 0; kh < 2; ++kh) {
        const int byte = lr * 128 + kh * 64 + g * 16;
        const int phys = byte ^ ((lr & 7) << 4);
        af[mi][kh] = *(const short8*)((const char*)&lds[tt][0][mh][0] + phys);
      }
    }
  };
  auto ld_b = [&](short8 (&bf)[2][2], int tt, int nh) {
#pragma unroll
    for (int nj = 0; nj < 2; ++nj) {
      const int lc = wb * 32 + nj * 16 + fr;
#pragma unroll
      for (int kh = 0; kh < 2; ++kh) {
        const int byte = lc * 128 + kh * 64 + g * 16;
        const int phys = byte ^ ((lc & 7) << 4);
        bf[nj][kh] = *(const short8*)((const char*)&lds[tt][1][nh][0] + phys);
      }
    }
  };

  f32x4 acc[2][2][4][2];
#pragma unroll
  for (int mh = 0; mh < 2; ++mh)
#pragma unroll
    for (int nh = 0; nh < 2; ++nh)
#pragma unroll
      for (int mi = 0; mi < 4; ++mi)
#pragma unroll
        for (int nj = 0; nj < 2; ++nj)
          for (int r = 0; r < 4; ++r) acc[mh][nh][mi][nj][r] = 0.f;

  // prologue: tile0 fully, tile1 halves A0,B0 -> 12 loads; keep newest 4 in flight
  stage_half(0, 0, 0, 0); stage_half(0, 0, 1, 0);
  stage_half(0, 1, 0, 0); stage_half(0, 1, 1, 0);
  stage_half(1, 0, 0, 1); stage_half(1, 1, 0, 1);
  asm volatile("s_waitcnt vmcnt(4)" ::: "memory");
  BARRIER_FENCED();

  for (int it = 0; it < (nk >> 1); ++it) {
    const int T = it << 1;
#pragma unroll
    for (int tt = 0; tt < 2; ++tt) {
      short8 af[4][2], b0[2][2], b1[2][2];

      // ---- phase q=0: quadrant (0,0); read A0 + B0 ----
      ld_a(af, tt, 0);
      ld_b(b0, tt, 0);
      if (tt == 0) stage_half(1, 0, 1, T + 1);
      else if (T + 2 < nk) stage_half(0, 0, 1, T + 2);
      BARRIER_FENCED();
      __builtin_amdgcn_s_setprio(1);
#pragma unroll
      for (int mi = 0; mi < 4; ++mi)
#pragma unroll
        for (int nj = 0; nj < 2; ++nj)
#pragma unroll
          for (int kh = 0; kh < 2; ++kh)
            acc[0][0][mi][nj] = mfma_bf16(af[mi][kh], b0[nj][kh], acc[0][0][mi][nj]);
      __builtin_amdgcn_s_setprio(0);
      BARRIER_FENCED();

      // ---- phase q=1: quadrant (0,1); read B1, reuse A0 ----
      ld_b(b1, tt, 1);
      if (tt == 0) stage_half(1, 1, 1, T + 1);
      else if (T + 2 < nk) stage_half(0, 1, 1, T + 2);
      BARRIER_FENCED();
      __builtin_amdgcn_s_setprio(1);
#pragma unroll
      for (int mi = 0; mi < 4; ++mi)
#pragma unroll
        for (int nj = 0; nj < 2; ++nj)
#pragma unroll
          for (int kh = 0; kh < 2; ++kh)
            acc[0][1][mi][nj] = mfma_bf16(af[mi][kh], b1[nj][kh], acc[0][1][mi][nj]);
      __builtin_amdgcn_s_setprio(0);
      BARRIER_FENCED();

      // ---- phase q=2: quadrant (1,1); read A1, reuse B1 ----
      ld_a(af, tt, 1);
      if (tt == 0) { if (T + 2 < nk) stage_half(0, 0, 0, T + 2); }
      else         { if (T + 3 < nk) stage_half(1, 0, 0, T + 3); }
      BARRIER_FENCED();
      __builtin_amdgcn_s_setprio(1);
#pragma unroll
      for (int mi = 0; mi < 4; ++mi)
#pragma unroll
        for (int nj = 0; nj < 2; ++nj)
#pragma unroll
          for (int kh = 0; kh < 2; ++kh)
            acc[1][1][mi][nj] = mfma_bf16(af[mi][kh], b1[nj][kh], acc[1][1][mi][nj]);
      __builtin_amdgcn_s_setprio(0);
      BARRIER_FENCED();

      // ---- phase q=3: quadrant (1,0); no reads (reuse A1 + B0) ----
      if (tt == 0) { if (T + 2 < nk) stage_half(0, 1, 0, T + 2); }
      else         { if (T + 3 < nk) stage_half(1, 1, 0, T + 3); }
      BARRIER_FENCED();
      __builtin_amdgcn_s_setprio(1);
#pragma unroll
      for (int mi = 0; mi < 4; ++mi)
#pragma unroll
        for (int nj = 0; nj < 2; ++nj)
#pragma unroll
          for (int kh = 0; kh < 2; ++kh)
            acc[1][0][mi][nj] = mfma_bf16(af[mi][kh], b0[nj][kh], acc[1][0][mi][nj]);
      __builtin_amdgcn_s_setprio(0);
      if (tt == 0) {
        if (T + 2 < nk) asm volatile("s_waitcnt vmcnt(4)" ::: "memory");
        else            asm volatile("s_waitcnt vmcnt(0)" ::: "memory");
      } else {
        if (T + 3 < nk) asm volatile("s_waitcnt vmcnt(4)" ::: "memory");
        else            asm volatile("s_waitcnt vmcnt(0)" ::: "memory");
      }
      BARRIER_FENCED();
    }
  }

  // ---- epilogue: C-write (col = lane&15, row = (lane>>4)*4 + r) ----
  const int cr = (lane >> 4) * 4, ccol = lane & 15;
#pragma unroll
  for (int mh = 0; mh < 2; ++mh)
#pragma unroll
    for (int nh = 0; nh < 2; ++nh)
#pragma unroll
      for (int mi = 0; mi < 4; ++mi)
#pragma unroll
        for (int nj = 0; nj < 2; ++nj) {
          const int row0 = bm + mh * 128 + wa * 64 + mi * 16 + cr;
          const int col  = bn + nh * 128 + wb * 32 + nj * 16 + ccol;
#pragma unroll
          for (int r = 0; r < 4; ++r) {
            if (OUTF32)
              ((float*)Cv)[(size_t)(row0 + r) * N + col] = acc[mh][nh][mi][nj][r];
            else
              ((short*)Cv)[(size_t)(row0 + r) * N + col] = f2bf_bits(acc[mh][nh][mi][nj][r]);
          }
        }
}

// ---------------------------------------------------------------------------
// RMSNorm over qckv[:, 3072:3584] -> ckvn (bf16).
// ---------------------------------------------------------------------------
__global__ __launch_bounds__(256)
void rmsnorm_k(const short* __restrict__ qckv, const float* __restrict__ w,
               short* __restrict__ out) {
  const int s = blockIdx.x, t = threadIdx.x;
  const short* x = qckv + (size_t)s * QCKV_LD + QN;
  float v0 = bf2f(x[2 * t]), v1 = bf2f(x[2 * t + 1]);
  float ss = v0 * v0 + v1 * v1;
#pragma unroll
  for (int off = 1; off < 64; off <<= 1) ss += __shfl_xor(ss, off, 64);
  __shared__ float red[4];
  if ((t & 63) == 0) red[t >> 6] = ss;
  __syncthreads();
  const float tot = red[0] + red[1] + red[2] + red[3];
  const float sc = rsqrtf(tot * (1.0f / 512.0f) + 1e-6f);
  out[(size_t)s * KV_R + 2 * t]     = f2bf_bits(v0 * sc * w[2 * t]);
  out[(size_t)s * KV_R + 2 * t + 1] = f2bf_bits(v1 * sc * w[2 * t + 1]);
}

// ---------------------------------------------------------------------------
// Prep: RoPE (deinterleaved) + assemble Qs[h][s][192], Ks[h][s][192].
// ---------------------------------------------------------------------------
__global__ __launch_bounds__(256)
void prep_k(const short* __restrict__ qckv, const short* __restrict__ kvb,
            const float* __restrict__ cosb, const float* __restrict__ sinb,
            short* __restrict__ Qs, short* __restrict__ Ks) {
  const int s = blockIdx.x, t = threadIdx.x;
  const short* qrow = qckv + (size_t)s * QCKV_LD;
  __shared__ float cs[32], sn[32];
  __shared__ short krs[64];
  if (t < 32) {
    const float c  = cosb[(size_t)s * 64 + t];
    const float si = sinb[(size_t)s * 64 + t];
    cs[t] = c; sn[t] = si;
    const float e0 = bf2f(qrow[QN + KV_R + 2 * t]);
    const float e1 = bf2f(qrow[QN + KV_R + 2 * t + 1]);
    krs[t]      = f2bf_bits(e0 * c - e1 * si);
    krs[t + 32] = f2bf_bits(e1 * c + e0 * si);
  }
  __syncthreads();
  const int h = t >> 4, i = t & 15;
  *(short8*)(Qs + ((size_t)h * S_LEN + s) * D_QK + i * 8) =
      *(const short8*)(qrow + h * D_QK + i * 8);
  *(short8*)(Ks + ((size_t)h * S_LEN + s) * D_QK + i * 8) =
      *(const short8*)(kvb + (size_t)s * KVB_N + h * 256 + i * 8);
#pragma unroll
  for (int p = 0; p < 2; ++p) {
    const int ii = i * 2 + p;  // 0..31
    const float e0 = bf2f(qrow[h * D_QK + 128 + 2 * ii]);
    const float e1 = bf2f(qrow[h * D_QK + 128 + 2 * ii + 1]);
    Qs[((size_t)h * S_LEN + s) * D_QK + 128 + ii] = f2bf_bits(e0 * cs[ii] - e1 * sn[ii]);
    Qs[((size_t)h * S_LEN + s) * D_QK + 160 + ii] = f2bf_bits(e1 * cs[ii] + e0 * sn[ii]);
  }
#pragma unroll
  for (int p = 0; p < 4; ++p) {
    const int idx = t * 4 + p;          // 0..1023
    const int hh = idx >> 6, ii = idx & 63;
    Ks[((size_t)hh * S_LEN + s) * D_QK + 128 + ii] = krs[ii];
  }
}

// ---------------------------------------------------------------------------
// V transpose via LDS tile: Vt[h][d][s] = kvb[s][h*256+128+d].
// ---------------------------------------------------------------------------
__global__ __launch_bounds__(256)
void vtr_k(const short* __restrict__ kvb, short* __restrict__ Vt) {
  const int st = blockIdx.x, dt = blockIdx.y, h = blockIdx.z;
  __shared__ short sT[64][72];
  const int id = threadIdx.x;
#pragma unroll
  for (int p = 0; p < 2; ++p) {
    const int q = id + p * 256;
    const int row = q >> 3, c8 = q & 7;
    *(short8*)(&sT[row][c8 * 8]) =
        *(const short8*)(kvb + (size_t)(st * 64 + row) * KVB_N + h * 256 + 128 + dt * 64 + c8 * 8);
  }
  __syncthreads();
#pragma unroll
  for (int p = 0; p < 2; ++p) {
    const int q = id + p * 256;
    const int drow = q >> 3, c8 = q & 7;
    short8 o;
#pragma unroll
    for (int j = 0; j < 8; ++j) o[j] = sT[c8 * 8 + j][drow];
    *(short8*)(Vt + ((size_t)h * D_V + dt * 64 + drow) * S_LEN + st * 64 + c8 * 8) = o;
  }
}

// ---------------------------------------------------------------------------
// Flash attention (Round-0 version, measured ~86 us): 512 blocks, one 64-row
// q-tile per block, heavy-first, 2 blocks/CU, register-prefetch pipeline.
// ---------------------------------------------------------------------------
__global__ __launch_bounds__(256, 2)
void flash_k(const short* __restrict__ Qs, const short* __restrict__ Ks,
             const short* __restrict__ Vt, short* __restrict__ Oc) {
  __shared__ short sK[64 * 200];        // 25.6 KB
  __shared__ short sVt[128 * 72];       // 18.4 KB
  __shared__ short P_lds[4][16 * 72];   //  9.2 KB
  const int tid = threadIdx.x;
  const int wv = tid >> 6;
  const int lane = tid & 63;
  const int blk = blockIdx.x;                          // 0..511
  const int h = ((blk & 7) << 1) | ((blk >> 3) & 1);   // 2 heads per XCD
  const int qb = 31 - (blk >> 4);                      // heavy q-blocks first
  const int q0 = qb * 64 + wv * 16;
  const int fr = lane & 15, g = lane >> 4;

  const short* Qh = Qs + (size_t)h * S_LEN * D_QK;
  const short* Kh = Ks + (size_t)h * S_LEN * D_QK;
  const short* Vh = Vt + (size_t)h * D_V * S_LEN;

  // loop-invariant staging coordinates
  int rowK[6], c8K[6], rowV[4], c8V[4];
#pragma unroll
  for (int p = 0; p < 6; ++p) {
    const int id = tid + p * 256;
    rowK[p] = id / 24; c8K[p] = id % 24;
  }
#pragma unroll
  for (int p = 0; p < 4; ++p) {
    const int id = tid + p * 256;
    rowV[p] = id >> 3; c8V[p] = id & 7;
  }

  short8 qa[6];
#pragma unroll
  for (int c = 0; c < 6; ++c)
    qa[c] = *(const short8*)(Qh + (size_t)(q0 + fr) * D_QK + c * 32 + g * 8);

  f32x4 o[8];
  for (int f = 0; f < 8; ++f)
    for (int r = 0; r < 4; ++r) o[f][r] = 0.f;
  float m_i[4] = {-1e30f, -1e30f, -1e30f, -1e30f};
  float l_i[4] = {0.f, 0.f, 0.f, 0.f};

  // prefetch tile 0
  short8 kc[6], vc[4];
#pragma unroll
  for (int p = 0; p < 6; ++p)
    kc[p] = *(const short8*)(Kh + (size_t)rowK[p] * D_QK + c8K[p] * 8);
#pragma unroll
  for (int p = 0; p < 4; ++p)
    vc[p] = *(const short8*)(Vh + (size_t)rowV[p] * S_LEN + c8V[p] * 8);

  short* pl = &P_lds[wv][0];
  const int jn = qb + 1;
  for (int jt = 0; jt < jn; ++jt) {
    const int j0 = jt << 6;
    // ---- commit prefetched tile to LDS ----
    __syncthreads();
#pragma unroll
    for (int p = 0; p < 6; ++p)
      *(short8*)(sK + rowK[p] * 200 + c8K[p] * 8) = kc[p];
#pragma unroll
    for (int p = 0; p < 4; ++p)
      *(short8*)(sVt + rowV[p] * 72 + c8V[p] * 8) = vc[p];
    __syncthreads();
    // ---- issue next tile's global loads (consumed next iteration) ----
    if (jt + 1 < jn) {
      const int j1 = (jt + 1) << 6;
#pragma unroll
      for (int p = 0; p < 6; ++p)
        kc[p] = *(const short8*)(Kh + (size_t)(j1 + rowK[p]) * D_QK + c8K[p] * 8);
#pragma unroll
      for (int p = 0; p < 4; ++p)
        vc[p] = *(const short8*)(Vh + (size_t)rowV[p] * S_LEN + j1 + c8V[p] * 8);
    }

    // ---- QK^T from LDS; skip fully-masked 16-key sub-tiles (wave-uniform) --
    f32x4 sc[4];
#pragma unroll
    for (int t = 0; t < 4; ++t)
      for (int r = 0; r < 4; ++r) sc[t][r] = -1e30f;
#pragma unroll
    for (int t = 0; t < 4; ++t) {
      if (j0 + t * 16 <= q0 + 15) {
        f32x4 a;
        for (int r = 0; r < 4; ++r) a[r] = 0.f;
        const short* kr = sK + (t * 16 + fr) * 200 + g * 8;
#pragma unroll
        for (int c = 0; c < 6; ++c)
          a = mfma_bf16(qa[c], *(const short8*)(kr + c * 32), a);
        sc[t] = a;
      }
    }
    // ---- scale + causal mask + per-row tile max ----
    float tm[4];
#pragma unroll
    for (int r = 0; r < 4; ++r) {
      const int row = q0 + g * 4 + r;
      float mx = -1e30f;
#pragma unroll
      for (int t = 0; t < 4; ++t) {
        const float v = (j0 + t * 16 + fr <= row) ? sc[t][r] * SCALING : -1e30f;
        sc[t][r] = v;
        mx = fmaxf(mx, v);
      }
      tm[r] = mx;
    }
#pragma unroll
    for (int off = 1; off < 16; off <<= 1)
#pragma unroll
      for (int r = 0; r < 4; ++r)
        tm[r] = fmaxf(tm[r], __shfl_xor(tm[r], off, 16));
    // ---- online softmax update ----
    float ps[4];
#pragma unroll
    for (int r = 0; r < 4; ++r) {
      const float mnew = fmaxf(m_i[r], tm[r]);
      const float alpha = __expf(m_i[r] - mnew);
      m_i[r] = mnew;
      l_i[r] *= alpha;
      float s = 0.f;
#pragma unroll
      for (int t = 0; t < 4; ++t) {
        const float p = __expf(sc[t][r] - mnew);
        sc[t][r] = p;
        s += p;
      }
      ps[r] = s;
#pragma unroll
      for (int f = 0; f < 8; ++f) o[f][r] *= alpha;
    }
#pragma unroll
    for (int off = 1; off < 16; off <<= 1)
#pragma unroll
      for (int r = 0; r < 4; ++r)
        ps[r] += __shfl_xor(ps[r], off, 16);
#pragma unroll
    for (int r = 0; r < 4; ++r) l_i[r] += ps[r];

    // ---- P (C-layout) -> per-wave LDS -> A-frag ----
#pragma unroll
    for (int r = 0; r < 4; ++r)
#pragma unroll
      for (int t = 0; t < 4; ++t)
        pl[(g * 4 + r) * 72 + t * 16 + fr] = f2bf_bits(sc[t][r]);
    __builtin_amdgcn_fence(__ATOMIC_ACQ_REL, "wavefront");
    const short8 pa0 = *(const short8*)(pl + fr * 72 + g * 8);
    const short8 pa1 = *(const short8*)(pl + fr * 72 + 32 + g * 8);

    // ---- PV from LDS V^T tile ----
#pragma unroll
    for (int f = 0; f < 8; ++f) {
      const short* vr = sVt + (f * 16 + fr) * 72 + g * 8;
      const short8 vb0 = *(const short8*)(vr);
      const short8 vb1 = *(const short8*)(vr + 32);
      o[f] = mfma_bf16(pa1, vb1, mfma_bf16(pa0, vb0, o[f]));
    }
  }

#pragma unroll
  for (int r = 0; r < 4; ++r) {
    const float inv = 1.0f / l_i[r];
    const int row = q0 + g * 4 + r;
#pragma unroll
    for (int f = 0; f < 8; ++f)
      Oc[(size_t)row * (NH * D_V) + h * D_V + f * 16 + fr] = f2bf_bits(o[f][r] * inv);
  }
}

// ---------------------------------------------------------------------------
extern "C" void kernel_launch(void* const* d_in, const int* in_sizes, int n_in,
                              void* d_out, int out_size, void* d_ws, size_t ws_size,
                              hipStream_t stream) {
  const float* hidden = (const float*)d_in[0];
  const float* cosb   = (const float*)d_in[1];
  const float* sinb   = (const float*)d_in[2];
  /* d_in[3] attention_mask: causal, applied analytically */
  const float* q_w    = (const float*)d_in[4];
  const float* kva_w  = (const float*)d_in[5];
  const float* ln_w   = (const float*)d_in[6];
  const float* kvb_w  = (const float*)d_in[7];
  const float* o_w    = (const float*)d_in[8];
  float* out = (float*)d_out;

  char* ws = (char*)d_ws;
  size_t off = 0;
  auto alloc = [&](size_t elems) {
    short* p = (short*)(ws + off);
    off += ((elems * 2 + 255) & ~(size_t)255);
    return p;
  };
  short* hid_b   = alloc((size_t)S_LEN * HID_DIM);
  short* qkva_wb = alloc((size_t)QKVA_ROWS * HID_DIM); // q_w rows, kva_w rows, zero pad
  short* kvb_wb  = alloc((size_t)KVB_N * KV_R);
  short* o_wb    = alloc((size_t)HID_DIM * NH * D_V);
  short* qckv    = alloc((size_t)S_LEN * QCKV_LD);     // fused q + ckv output (padded)
  short* ckvn    = alloc((size_t)S_LEN * KV_R);
  short* kvb     = alloc((size_t)S_LEN * KVB_N);
  short* Qs      = alloc((size_t)NH * S_LEN * D_QK);
  short* Ks      = alloc((size_t)NH * S_LEN * D_QK);
  short* Vt      = alloc((size_t)NH * D_V * S_LEN);
  short* Oc      = alloc((size_t)S_LEN * NH * D_V);

  dim3 blk(256);
  // zero the padded weight rows (3648..3839) so padded GEMM columns are finite
  hipMemsetAsync(qkva_wb + (size_t)CAT_N * HID_DIM, 0,
                 (size_t)(QKVA_ROWS - CAT_N) * HID_DIM * 2, stream);

  const int n0 = (S_LEN * HID_DIM) / 4;
  const int n1 = (QN * HID_DIM) / 4;
  const int n2 = (CKV_N * HID_DIM) / 4;
  const int n3 = (KVB_N * KV_R) / 4;
  const int n4e = (HID_DIM * NH * D_V) / 4;
  const int c0 = n0, c1 = c0 + n1, c2 = c1 + n2, c3 = c2 + n3, c4 = c3 + n4e;
  cvt5_k<<<dim3((c4 + 255) / 256), blk, 0, stream>>>(
      hidden, hid_b, c0,
      q_w, qkva_wb, c1,
      kva_w, qkva_wb + (size_t)QN * HID_DIM, c2,
      kvb_w, kvb_wb, c3,
      o_w, o_wb, c4);

  gemm8_k<false><<<dim3(QKVA_ROWS / 256, S_LEN / 256), dim3(512), 0, stream>>>(
      hid_b, qkva_wb, qckv, S_LEN, QKVA_ROWS, HID_DIM);
  rmsnorm_k<<<dim3(S_LEN), blk, 0, stream>>>(qckv, ln_w, ckvn);
  gemm8_k<false><<<dim3(KVB_N / 256, S_LEN / 256), dim3(512), 0, stream>>>(
      ckvn, kvb_wb, kvb, S_LEN, KVB_N, KV_R);
  prep_k<<<dim3(S_LEN), blk, 0, stream>>>(qckv, kvb, cosb, sinb, Qs, Ks);
  vtr_k<<<dim3(S_LEN / 64, D_V / 64, NH), blk, 0, stream>>>(kvb, Vt);
  flash_k<<<dim3(NH * 128 / 4), blk, 0, stream>>>(Qs, Ks, Vt, Oc);
  gemm8_k<true><<<dim3(HID_DIM / 256, S_LEN / 256), dim3(512), 0, stream>>>(
      Oc, o_wb, out, S_LEN, HID_DIM, NH * D_V);
}